// Round 3
// baseline (402.938 us; speedup 1.0000x reference)
//
#include <hip/hip_runtime.h>
#include <hip/hip_bf16.h>

#define DIM 512
#define DIM2 1024
#define NGRAPH 512
#define LN_EPS 1e-5f
#define NSEG 8   // row-segments per graph in the pooling reduction

// ---------------------------------------------------------------------------
// K0: zero the atomic accumulation buffer (re-runs every call: graph replay).
// ---------------------------------------------------------------------------
__global__ __launch_bounds__(256) void zero_kernel(float4* __restrict__ p, int n4) {
    int i = blockIdx.x * 256 + threadIdx.x;
    const int stride = gridDim.x * 256;
    for (; i < n4; i += stride) p[i] = make_float4(0.f, 0.f, 0.f, 0.f);
}

// ---------------------------------------------------------------------------
// K1: segment SUM pooling, 8 segments per graph for TLP (4096 blocks,
// 32 waves/CU). batch_idx sorted -> binary-search graph boundaries, each
// segment sums its row slice with an 8-row unrolled float4 stream, then
// atomicAdds its 512-float partial into sums[g] (L2-resident, 1 MB).
// Mean division is folded into GEMM1.
// ---------------------------------------------------------------------------
__global__ __launch_bounds__(128) void segsum_kernel(const float4* __restrict__ x4,
                                                     const int* __restrict__ bi,
                                                     float* __restrict__ sums,
                                                     int n_nodes) {
    const int g = blockIdx.x;
    __shared__ int sb[2];
    if (threadIdx.x < 2) {
        int v = g + (int)threadIdx.x;
        int lo = 0, hi = n_nodes;
        while (lo < hi) {
            int mid = (lo + hi) >> 1;
            if (bi[mid] < v) lo = mid + 1; else hi = mid;
        }
        sb[threadIdx.x] = lo;
    }
    __syncthreads();
    const int glo = sb[0], len = sb[1] - sb[0];
    const int s = blockIdx.y;
    const int r0 = glo + (len * s) / NSEG;
    const int r1 = glo + (len * (s + 1)) / NSEG;
    const int t = threadIdx.x;  // float4 column

    float4 a0 = {0,0,0,0}, a1 = {0,0,0,0}, a2 = {0,0,0,0}, a3 = {0,0,0,0};
    float4 a4 = {0,0,0,0}, a5 = {0,0,0,0}, a6 = {0,0,0,0}, a7 = {0,0,0,0};

    int r = r0;
    for (; r + 8 <= r1; r += 8) {
        float4 v0 = x4[(size_t)(r + 0) * 128 + t];
        float4 v1 = x4[(size_t)(r + 1) * 128 + t];
        float4 v2 = x4[(size_t)(r + 2) * 128 + t];
        float4 v3 = x4[(size_t)(r + 3) * 128 + t];
        float4 v4 = x4[(size_t)(r + 4) * 128 + t];
        float4 v5 = x4[(size_t)(r + 5) * 128 + t];
        float4 v6 = x4[(size_t)(r + 6) * 128 + t];
        float4 v7 = x4[(size_t)(r + 7) * 128 + t];
        a0.x += v0.x; a0.y += v0.y; a0.z += v0.z; a0.w += v0.w;
        a1.x += v1.x; a1.y += v1.y; a1.z += v1.z; a1.w += v1.w;
        a2.x += v2.x; a2.y += v2.y; a2.z += v2.z; a2.w += v2.w;
        a3.x += v3.x; a3.y += v3.y; a3.z += v3.z; a3.w += v3.w;
        a4.x += v4.x; a4.y += v4.y; a4.z += v4.z; a4.w += v4.w;
        a5.x += v5.x; a5.y += v5.y; a5.z += v5.z; a5.w += v5.w;
        a6.x += v6.x; a6.y += v6.y; a6.z += v6.z; a6.w += v6.w;
        a7.x += v7.x; a7.y += v7.y; a7.z += v7.z; a7.w += v7.w;
    }
    for (; r < r1; ++r) {
        float4 v0 = x4[(size_t)r * 128 + t];
        a0.x += v0.x; a0.y += v0.y; a0.z += v0.z; a0.w += v0.w;
    }
    a0.x += a1.x + a2.x + a3.x + a4.x + a5.x + a6.x + a7.x;
    a0.y += a1.y + a2.y + a3.y + a4.y + a5.y + a6.y + a7.y;
    a0.z += a1.z + a2.z + a3.z + a4.z + a5.z + a6.z + a7.z;
    a0.w += a1.w + a2.w + a3.w + a4.w + a5.w + a6.w + a7.w;

    float* dst = sums + (size_t)g * DIM + t * 4;
    atomicAdd(dst + 0, a0.x);
    atomicAdd(dst + 1, a0.y);
    atomicAdd(dst + 2, a0.z);
    atomicAdd(dst + 3, a0.w);
}

// ---------------------------------------------------------------------------
// K2: h1 = relu((sums * inv_count) @ W1 + b1), with the per-row 1/count
// folded in after the K-loop:  (sum_k S[r,k]*W[k,c]) * inv[r] + b1[c].
// Row counts come from binary searches on the sorted batch_idx.
// grid = (4 col-blocks of 256, 64 row-blocks of 8).
// ---------------------------------------------------------------------------
__global__ __launch_bounds__(256) void gemm1_kernel(const float* __restrict__ S,
                                                    const int* __restrict__ bi,
                                                    const float* __restrict__ W1,
                                                    const float* __restrict__ b1,
                                                    float* __restrict__ h1,
                                                    int n_nodes) {
    const int col = blockIdx.x * 256 + threadIdx.x;
    const int r0 = blockIdx.y * 8;
    __shared__ int sb[9];
    if (threadIdx.x < 9) {
        int v = r0 + (int)threadIdx.x;
        int lo = 0, hi = n_nodes;
        while (lo < hi) {
            int mid = (lo + hi) >> 1;
            if (bi[mid] < v) lo = mid + 1; else hi = mid;
        }
        sb[threadIdx.x] = lo;
    }
    __syncthreads();
    float inv[8];
#pragma unroll
    for (int r = 0; r < 8; ++r) {
        int c = sb[r + 1] - sb[r];
        inv[r] = 1.0f / (float)(c > 0 ? c : 1);
    }
    float acc[8] = {0,0,0,0,0,0,0,0};
#pragma unroll 8
    for (int k = 0; k < DIM; ++k) {
        float w = W1[(size_t)k * DIM2 + col];
#pragma unroll
        for (int r = 0; r < 8; ++r)
            acc[r] += S[(size_t)(r0 + r) * DIM + k] * w;
    }
    float bb = b1[col];
#pragma unroll
    for (int r = 0; r < 8; ++r) {
        float v = acc[r] * inv[r] + bb;
        h1[(size_t)(r0 + r) * DIM2 + col] = v > 0.0f ? v : 0.0f;
    }
}

// ---------------------------------------------------------------------------
// K3: h2 = h1 @ W2 + b2.  grid = (2 col-blocks of 256, 64 row-blocks of 8).
// ---------------------------------------------------------------------------
__global__ __launch_bounds__(256) void gemm2_kernel(const float* __restrict__ A,
                                                    const float* __restrict__ W2,
                                                    const float* __restrict__ b2,
                                                    float* __restrict__ h2) {
    const int col = blockIdx.x * 256 + threadIdx.x;
    const int r0 = blockIdx.y * 8;
    float acc[8] = {0,0,0,0,0,0,0,0};
#pragma unroll 8
    for (int k = 0; k < DIM2; ++k) {
        float w = W2[(size_t)k * DIM + col];
#pragma unroll
        for (int r = 0; r < 8; ++r)
            acc[r] += A[(size_t)(r0 + r) * DIM2 + k] * w;
    }
    float bb = b2[col];
#pragma unroll
    for (int r = 0; r < 8; ++r)
        h2[(size_t)(r0 + r) * DIM + col] = acc[r] + bb;
}

// ---------------------------------------------------------------------------
// K4: LayerNorm over last dim; writes h_vn into d_out tail (output 1).
// ---------------------------------------------------------------------------
__global__ __launch_bounds__(256) void ln_kernel(const float* __restrict__ h2,
                                                 const float* __restrict__ gamma,
                                                 const float* __restrict__ beta,
                                                 float* __restrict__ out) {
    const int row = blockIdx.x;
    const int t = threadIdx.x;
    const float* hr = h2 + (size_t)row * DIM;
    float v0 = hr[t], v1 = hr[t + 256];
    float s = v0 + v1;
    float ss = v0 * v0 + v1 * v1;
#pragma unroll
    for (int off = 32; off > 0; off >>= 1) {
        s  += __shfl_xor(s,  off);
        ss += __shfl_xor(ss, off);
    }
    __shared__ float sh_s[4], sh_ss[4];
    int wid = t >> 6, lane = t & 63;
    if (lane == 0) { sh_s[wid] = s; sh_ss[wid] = ss; }
    __syncthreads();
    s  = sh_s[0] + sh_s[1] + sh_s[2] + sh_s[3];
    ss = sh_ss[0] + sh_ss[1] + sh_ss[2] + sh_ss[3];
    float mu  = s * (1.0f / DIM);
    float var = ss * (1.0f / DIM) - mu * mu;
    float rs  = rsqrtf(var + LN_EPS);
    out[(size_t)row * DIM + t]       = (v0 - mu) * rs * gamma[t]       + beta[t];
    out[(size_t)row * DIM + t + 256] = (v1 - mu) * rs * gamma[t + 256] + beta[t + 256];
}

// ---------------------------------------------------------------------------
// K5: x_new = x + h_vn[batch_idx].  float4 grid-stride; h_vn (1 MB)
// L2/L3-resident.
// ---------------------------------------------------------------------------
__global__ __launch_bounds__(256) void resid_kernel(const float4* __restrict__ x4,
                                                    const int* __restrict__ bi,
                                                    const float4* __restrict__ hv4,
                                                    float4* __restrict__ out4,
                                                    int n4) {
    const int stride = gridDim.x * blockDim.x;
    for (int i = blockIdx.x * 256 + threadIdx.x; i < n4; i += stride) {
        int row = i >> 7;          // 128 float4 per row
        int c   = i & 127;
        int g   = bi[row];
        float4 xv = x4[i];
        float4 hv = hv4[(g << 7) + c];
        float4 o;
        o.x = xv.x + hv.x; o.y = xv.y + hv.y;
        o.z = xv.z + hv.z; o.w = xv.w + hv.w;
        out4[i] = o;
    }
}

extern "C" void kernel_launch(void* const* d_in, const int* in_sizes, int n_in,
                              void* d_out, int out_size, void* d_ws, size_t ws_size,
                              hipStream_t stream) {
    const float* x     = (const float*)d_in[0];
    const int*   bidx  = (const int*)d_in[1];   // int32 per harness contract
    const float* W1    = (const float*)d_in[2];
    const float* b1    = (const float*)d_in[3];
    const float* W2    = (const float*)d_in[4];
    const float* b2    = (const float*)d_in[5];
    const float* gamma = (const float*)d_in[6];
    const float* beta  = (const float*)d_in[7];

    const int n_nodes = in_sizes[1];
    const size_t x_elems = (size_t)n_nodes * DIM;

    float* out     = (float*)d_out;
    float* x_new   = out;                 // output 0: [n_nodes, 512]
    float* hvn_out = out + x_elems;       // output 1: [512, 512]

    // workspace layout (4 MB total)
    float* sums = (float*)d_ws;                     // 512*512 (atomic acc)
    float* h1   = sums + (size_t)NGRAPH * DIM;      // 512*1024
    float* h2   = h1 + (size_t)NGRAPH * DIM2;       // 512*512

    // K0: zero atomic buffer (1 MB)
    zero_kernel<<<128, 256, 0, stream>>>((float4*)sums, NGRAPH * DIM / 4);
    // K1: segment sums, 8 segments/graph
    segsum_kernel<<<dim3(NGRAPH, NSEG), 128, 0, stream>>>((const float4*)x, bidx,
                                                          sums, n_nodes);
    // K2: relu((sums/count) @ W1 + b1), mean folded in
    gemm1_kernel<<<dim3(4, 64), 256, 0, stream>>>(sums, bidx, W1, b1, h1, n_nodes);
    // K3: h1 @ W2 + b2
    gemm2_kernel<<<dim3(2, 64), 256, 0, stream>>>(h1, W2, b2, h2);
    // K4: LayerNorm -> output 1 (also consumed by K5)
    ln_kernel<<<NGRAPH, 256, 0, stream>>>(h2, gamma, beta, hvn_out);
    // K5: residual broadcast add -> output 0
    const int n4 = (int)(x_elems / 4);
    resid_kernel<<<4096, 256, 0, stream>>>((const float4*)x, bidx,
                                           (const float4*)hvn_out,
                                           (float4*)x_new, n4);
}

// Round 4
// 393.856 us; speedup vs baseline: 1.0231x; 1.0231x over previous
//
#include <hip/hip_runtime.h>
#include <hip/hip_bf16.h>

#define DIM 512
#define DIM2 1024
#define NGRAPH 512
#define LN_EPS 1e-5f
#define NSEG 8   // row-segments per graph in the pooling reduction

typedef float f4 __attribute__((ext_vector_type(4)));

__device__ __forceinline__ f4 ntl(const f4* p) { return __builtin_nontemporal_load(p); }
__device__ __forceinline__ void nts(f4* p, f4 v) { __builtin_nontemporal_store(v, p); }

// ---------------------------------------------------------------------------
// K0: zero the atomic accumulation buffer (re-runs every call: graph replay).
// ---------------------------------------------------------------------------
__global__ __launch_bounds__(256) void zero_kernel(f4* __restrict__ p, int n4) {
    int i = blockIdx.x * 256 + threadIdx.x;
    const int stride = gridDim.x * 256;
    f4 z = {0.f, 0.f, 0.f, 0.f};
    for (; i < n4; i += stride) p[i] = z;
}

// ---------------------------------------------------------------------------
// K1: segment SUM pooling, 8 segments/graph (4096 blocks). Nontemporal x
// reads keep L2 clean for bi / sums. Partials atomicAdd'ed into sums
// (1 MB, L2-resident). Mean division folded into GEMM1.
// ---------------------------------------------------------------------------
__global__ __launch_bounds__(128) void segsum_kernel(const f4* __restrict__ x4,
                                                     const int* __restrict__ bi,
                                                     float* __restrict__ sums,
                                                     int n_nodes) {
    const int g = blockIdx.x;
    __shared__ int sb[2];
    if (threadIdx.x < 2) {
        int v = g + (int)threadIdx.x;
        int lo = 0, hi = n_nodes;
        while (lo < hi) {
            int mid = (lo + hi) >> 1;
            if (bi[mid] < v) lo = mid + 1; else hi = mid;
        }
        sb[threadIdx.x] = lo;
    }
    __syncthreads();
    const int glo = sb[0], len = sb[1] - sb[0];
    const int s = blockIdx.y;
    const int r0 = glo + (len * s) / NSEG;
    const int r1 = glo + (len * (s + 1)) / NSEG;
    const int t = threadIdx.x;  // f4 column

    f4 a0 = {0,0,0,0}, a1 = {0,0,0,0}, a2 = {0,0,0,0}, a3 = {0,0,0,0};
    f4 a4 = {0,0,0,0}, a5 = {0,0,0,0}, a6 = {0,0,0,0}, a7 = {0,0,0,0};

    int r = r0;
    for (; r + 8 <= r1; r += 8) {
        f4 v0 = ntl(x4 + (size_t)(r + 0) * 128 + t);
        f4 v1 = ntl(x4 + (size_t)(r + 1) * 128 + t);
        f4 v2 = ntl(x4 + (size_t)(r + 2) * 128 + t);
        f4 v3 = ntl(x4 + (size_t)(r + 3) * 128 + t);
        f4 v4 = ntl(x4 + (size_t)(r + 4) * 128 + t);
        f4 v5 = ntl(x4 + (size_t)(r + 5) * 128 + t);
        f4 v6 = ntl(x4 + (size_t)(r + 6) * 128 + t);
        f4 v7 = ntl(x4 + (size_t)(r + 7) * 128 + t);
        a0 += v0; a1 += v1; a2 += v2; a3 += v3;
        a4 += v4; a5 += v5; a6 += v6; a7 += v7;
    }
    for (; r < r1; ++r) a0 += ntl(x4 + (size_t)r * 128 + t);

    a0 += a1 + a2 + a3 + a4 + a5 + a6 + a7;

    float* dst = sums + (size_t)g * DIM + t * 4;
    atomicAdd(dst + 0, a0[0]);
    atomicAdd(dst + 1, a0[1]);
    atomicAdd(dst + 2, a0[2]);
    atomicAdd(dst + 3, a0[3]);
}

// ---------------------------------------------------------------------------
// K2: h1 = relu((sums * inv_count) @ W1 + b1); 1/count folded in post-K-loop.
// grid = (4 col-blocks of 256, 64 row-blocks of 8).
// ---------------------------------------------------------------------------
__global__ __launch_bounds__(256) void gemm1_kernel(const float* __restrict__ S,
                                                    const int* __restrict__ bi,
                                                    const float* __restrict__ W1,
                                                    const float* __restrict__ b1,
                                                    float* __restrict__ h1,
                                                    int n_nodes) {
    const int col = blockIdx.x * 256 + threadIdx.x;
    const int r0 = blockIdx.y * 8;
    __shared__ int sb[9];
    if (threadIdx.x < 9) {
        int v = r0 + (int)threadIdx.x;
        int lo = 0, hi = n_nodes;
        while (lo < hi) {
            int mid = (lo + hi) >> 1;
            if (bi[mid] < v) lo = mid + 1; else hi = mid;
        }
        sb[threadIdx.x] = lo;
    }
    __syncthreads();
    float inv[8];
#pragma unroll
    for (int r = 0; r < 8; ++r) {
        int c = sb[r + 1] - sb[r];
        inv[r] = 1.0f / (float)(c > 0 ? c : 1);
    }
    float acc[8] = {0,0,0,0,0,0,0,0};
#pragma unroll 8
    for (int k = 0; k < DIM; ++k) {
        float w = W1[(size_t)k * DIM2 + col];
#pragma unroll
        for (int r = 0; r < 8; ++r)
            acc[r] += S[(size_t)(r0 + r) * DIM + k] * w;
    }
    float bb = b1[col];
#pragma unroll
    for (int r = 0; r < 8; ++r) {
        float v = acc[r] * inv[r] + bb;
        h1[(size_t)(r0 + r) * DIM2 + col] = v > 0.0f ? v : 0.0f;
    }
}

// ---------------------------------------------------------------------------
// K3: fused h2 = h1 @ W2 + b2 followed by LayerNorm, writing h_vn straight
// to the d_out tail. Block = 8 rows x 512 cols, 512 threads (1 col each).
// W2 col reads L2-resident; h1 row reads block-uniform (scalar path).
// ---------------------------------------------------------------------------
__global__ __launch_bounds__(512) void ffn2_ln_kernel(const float* __restrict__ h1,
                                                      const float* __restrict__ W2,
                                                      const float* __restrict__ b2,
                                                      const float* __restrict__ gamma,
                                                      const float* __restrict__ beta,
                                                      float* __restrict__ out) {
    const int col = threadIdx.x;          // 0..511
    const int r0 = blockIdx.x * 8;
    float acc[8] = {0,0,0,0,0,0,0,0};
#pragma unroll 8
    for (int k = 0; k < DIM2; ++k) {
        float w = W2[(size_t)k * DIM + col];
#pragma unroll
        for (int r = 0; r < 8; ++r)
            acc[r] += h1[(size_t)(r0 + r) * DIM2 + k] * w;
    }
    float bb = b2[col];
    float v[8];
#pragma unroll
    for (int r = 0; r < 8; ++r) v[r] = acc[r] + bb;

    // block-wide LayerNorm reduce for 8 rows
    __shared__ float sh_s[8][8], sh_ss[8][8];
    const int wid = threadIdx.x >> 6, lane = threadIdx.x & 63;
#pragma unroll
    for (int r = 0; r < 8; ++r) {
        float s = v[r], ss = v[r] * v[r];
#pragma unroll
        for (int off = 32; off > 0; off >>= 1) {
            s  += __shfl_xor(s,  off);
            ss += __shfl_xor(ss, off);
        }
        if (lane == 0) { sh_s[r][wid] = s; sh_ss[r][wid] = ss; }
    }
    __syncthreads();
    float gm = gamma[col], bt = beta[col];
#pragma unroll
    for (int r = 0; r < 8; ++r) {
        float s = 0.f, ss = 0.f;
#pragma unroll
        for (int w = 0; w < 8; ++w) { s += sh_s[r][w]; ss += sh_ss[r][w]; }
        float mu  = s * (1.0f / DIM);
        float var = ss * (1.0f / DIM) - mu * mu;
        float rs  = rsqrtf(var + LN_EPS);
        out[(size_t)(r0 + r) * DIM + col] = (v[r] - mu) * rs * gm + bt;
    }
}

// ---------------------------------------------------------------------------
// K4: x_new = x + h_vn[batch_idx]. 4x unrolled grid-stride: 4 independent
// nontemporal x loads in flight per lane; nontemporal stores keep L2 free
// for the h_vn gather table (1 MB) and bi.
// ---------------------------------------------------------------------------
__global__ __launch_bounds__(256) void resid_kernel(const f4* __restrict__ x4,
                                                    const int* __restrict__ bi,
                                                    const f4* __restrict__ hv4,
                                                    f4* __restrict__ out4,
                                                    int n4) {
    const int S = gridDim.x * 256;
    int i = blockIdx.x * 256 + threadIdx.x;
    for (; i + 3 * S < n4; i += 4 * S) {
        const int i0 = i, i1 = i + S, i2 = i + 2 * S, i3 = i + 3 * S;
        f4 x0 = ntl(x4 + i0), x1 = ntl(x4 + i1), x2 = ntl(x4 + i2), x3 = ntl(x4 + i3);
        int g0 = bi[i0 >> 7], g1 = bi[i1 >> 7], g2 = bi[i2 >> 7], g3 = bi[i3 >> 7];
        f4 h0 = hv4[(g0 << 7) + (i0 & 127)];
        f4 h1 = hv4[(g1 << 7) + (i1 & 127)];
        f4 h2 = hv4[(g2 << 7) + (i2 & 127)];
        f4 h3 = hv4[(g3 << 7) + (i3 & 127)];
        nts(out4 + i0, x0 + h0);
        nts(out4 + i1, x1 + h1);
        nts(out4 + i2, x2 + h2);
        nts(out4 + i3, x3 + h3);
    }
    for (; i < n4; i += S) {
        f4 xv = ntl(x4 + i);
        int g = bi[i >> 7];
        f4 hv = hv4[(g << 7) + (i & 127)];
        nts(out4 + i, xv + hv);
    }
}

extern "C" void kernel_launch(void* const* d_in, const int* in_sizes, int n_in,
                              void* d_out, int out_size, void* d_ws, size_t ws_size,
                              hipStream_t stream) {
    const float* x     = (const float*)d_in[0];
    const int*   bidx  = (const int*)d_in[1];   // int32 per harness contract
    const float* W1    = (const float*)d_in[2];
    const float* b1    = (const float*)d_in[3];
    const float* W2    = (const float*)d_in[4];
    const float* b2    = (const float*)d_in[5];
    const float* gamma = (const float*)d_in[6];
    const float* beta  = (const float*)d_in[7];

    const int n_nodes = in_sizes[1];
    const size_t x_elems = (size_t)n_nodes * DIM;

    float* out     = (float*)d_out;
    float* x_new   = out;                 // output 0: [n_nodes, 512]
    float* hvn_out = out + x_elems;       // output 1: [512, 512]

    // workspace layout
    float* sums = (float*)d_ws;                     // 512*512 (atomic acc)
    float* h1   = sums + (size_t)NGRAPH * DIM;      // 512*1024

    // K0: zero atomic buffer (1 MB)
    zero_kernel<<<128, 256, 0, stream>>>((f4*)sums, NGRAPH * DIM / 4);
    // K1: segment sums, 8 segments/graph
    segsum_kernel<<<dim3(NGRAPH, NSEG), 128, 0, stream>>>((const f4*)x, bidx,
                                                          sums, n_nodes);
    // K2: relu((sums/count) @ W1 + b1)
    gemm1_kernel<<<dim3(4, 64), 256, 0, stream>>>(sums, bidx, W1, b1, h1, n_nodes);
    // K3: fused (h1 @ W2 + b2) + LayerNorm -> output 1
    ffn2_ln_kernel<<<64, 512, 0, stream>>>(h1, W2, b2, gamma, beta, hvn_out);
    // K4: residual broadcast add -> output 0
    const int n4 = (int)(x_elems / 4);
    resid_kernel<<<4096, 256, 0, stream>>>((const f4*)x, bidx,
                                           (const f4*)hvn_out,
                                           (f4*)x_new, n4);
}